// Round 7
// baseline (177.349 us; speedup 1.0000x reference)
//
#include <hip/hip_runtime.h>
#include <hip/hip_bf16.h>
#include <stdint.h>

#define T_TOK 16384
#define D_DIM 1024
#define E_EXP 64
#define R_RANK 8
#define SCALE 0.125f

typedef __attribute__((ext_vector_type(8))) __bf16 bf16x8;
typedef __attribute__((ext_vector_type(4))) float f32x4;
typedef const __attribute__((address_space(3))) uint8_t* lds_ptr_t;

__device__ __forceinline__ uint16_t bf16_rne(float f) {
  union { float f; uint32_t u; } v; v.f = f;
  return (uint16_t)((v.u + 0x7fffu + ((v.u >> 16) & 1u)) >> 16);
}

__device__ __forceinline__ void gld_lds16(const void* g, void* l) {
  __builtin_amdgcn_global_load_lds(
      (const __attribute__((address_space(1))) uint32_t*)g,
      (__attribute__((address_space(3))) uint32_t*)l, 16, 0, 0);
}

// ---------------- prep: W [K][N] f32 -> Wt [N][K] bf16 (transposed) ----------
__global__ __launch_bounds__(256) void k_prep_w(const float* __restrict__ W,
                                                uint16_t* __restrict__ Wt) {
  __shared__ float tile[32][33];
  const int t = threadIdx.x;
  const int r0 = blockIdx.y * 32, c0 = blockIdx.x * 32;
  const int r = t >> 3, c = (t & 7) * 4;
  float4 v = *(const float4*)(W + (size_t)(r0 + r) * D_DIM + c0 + c);
  tile[r][c + 0] = v.x; tile[r][c + 1] = v.y;
  tile[r][c + 2] = v.z; tile[r][c + 3] = v.w;
  __syncthreads();
  const int n = t >> 3;
  const int kk = (t & 7) * 4;
  ushort4 o;
  o.x = bf16_rne(tile[kk + 0][n]);
  o.y = bf16_rne(tile[kk + 1][n]);
  o.z = bf16_rne(tile[kk + 2][n]);
  o.w = bf16_rne(tile[kk + 3][n]);
  *(ushort4*)(Wt + (size_t)(c0 + n) * D_DIM + r0 + kk) = o;
}

// ---------------- prep: B [E][R][N] f32 -> Bb [E][N][R] bf16 (transposed) ----
__global__ __launch_bounds__(256) void k_prep_b(const float* __restrict__ B,
                                                uint16_t* __restrict__ Bb) {
  const int idx = blockIdx.x * 256 + threadIdx.x;
  const int e = idx >> 10, n = idx & 1023;
  const float* src = B + (size_t)e * (R_RANK * D_DIM) + n;
  ushort4 o0, o1;
  o0.x = bf16_rne(src[0 * D_DIM]); o0.y = bf16_rne(src[1 * D_DIM]);
  o0.z = bf16_rne(src[2 * D_DIM]); o0.w = bf16_rne(src[3 * D_DIM]);
  o1.x = bf16_rne(src[4 * D_DIM]); o1.y = bf16_rne(src[5 * D_DIM]);
  o1.z = bf16_rne(src[6 * D_DIM]); o1.w = bf16_rne(src[7 * D_DIM]);
  *(ushort4*)(Bb + (size_t)idx * 8) = o0;
  *(ushort4*)(Bb + (size_t)idx * 8 + 4) = o1;
}

// ---------------- prep: A [E][D][R] f32 -> At [E][R][D] bf16 (transposed) ----
__global__ __launch_bounds__(256) void k_prep_a(const float* __restrict__ A,
                                                uint16_t* __restrict__ At) {
  const int idx = blockIdx.x * 256 + threadIdx.x;
  const int e = idx >> 10, d = idx & 1023;
  const float* src = A + (size_t)idx * R_RANK;
  float4 p0 = *(const float4*)(src);
  float4 p1 = *(const float4*)(src + 4);
  uint16_t* dst = At + (size_t)e * (R_RANK * D_DIM) + d;
  dst[0 * D_DIM] = bf16_rne(p0.x);
  dst[1 * D_DIM] = bf16_rne(p0.y);
  dst[2 * D_DIM] = bf16_rne(p0.z);
  dst[3 * D_DIM] = bf16_rne(p0.w);
  dst[4 * D_DIM] = bf16_rne(p1.x);
  dst[5 * D_DIM] = bf16_rne(p1.y);
  dst[6 * D_DIM] = bf16_rne(p1.z);
  dst[7 * D_DIM] = bf16_rne(p1.w);
}

// ---------------- prep: x -> bf16 copy + xa[t][r] (16B loads, 2 iters) -------
__global__ __launch_bounds__(256) void k_prep_x(const float* __restrict__ x,
                                                const int* __restrict__ labels,
                                                const uint16_t* __restrict__ At,
                                                uint16_t* __restrict__ xb,
                                                float* __restrict__ xa) {
  const int wid = threadIdx.x >> 6, lane = threadIdx.x & 63;
  const int tok = blockIdx.x * 4 + wid;
  const int lbl = labels[tok];
  const float* xrow = x + (size_t)tok * D_DIM;
  const uint16_t* Ab = At + (size_t)lbl * (R_RANK * D_DIM);
  float acc[8] = {0, 0, 0, 0, 0, 0, 0, 0};
#pragma unroll
  for (int it = 0; it < 2; ++it) {
    const int d = it * 512 + lane * 8;
    float4 xv0 = *(const float4*)(xrow + d);
    float4 xv1 = *(const float4*)(xrow + d + 4);
    ushort4 o0, o1;
    o0.x = bf16_rne(xv0.x); o0.y = bf16_rne(xv0.y);
    o0.z = bf16_rne(xv0.z); o0.w = bf16_rne(xv0.w);
    o1.x = bf16_rne(xv1.x); o1.y = bf16_rne(xv1.y);
    o1.z = bf16_rne(xv1.z); o1.w = bf16_rne(xv1.w);
    *(ushort4*)(xb + (size_t)tok * D_DIM + d) = o0;
    *(ushort4*)(xb + (size_t)tok * D_DIM + d + 4) = o1;
#pragma unroll
    for (int r = 0; r < 8; ++r) {
      bf16x8 av = *(const bf16x8*)(Ab + r * D_DIM + d);
      acc[r] += xv0.x * (float)av[0] + xv0.y * (float)av[1] +
                xv0.z * (float)av[2] + xv0.w * (float)av[3] +
                xv1.x * (float)av[4] + xv1.y * (float)av[5] +
                xv1.z * (float)av[6] + xv1.w * (float)av[7];
    }
  }
#pragma unroll
  for (int off = 32; off >= 1; off >>= 1) {
#pragma unroll
    for (int r = 0; r < 8; ++r) acc[r] += __shfl_xor(acc[r], off);
  }
  if (lane == 0) {
    float4 q0 = {acc[0], acc[1], acc[2], acc[3]};
    float4 q1 = {acc[4], acc[5], acc[6], acc[7]};
    *(float4*)(xa + (size_t)tok * 8) = q0;
    *(float4*)(xa + (size_t)tok * 8 + 4) = q1;
  }
}

// ============== main GEMM: 256x256 tile, BK=64, 5 barriers per kt ============
// kt entry: vmcnt(4) (per-wave: this kt's 8 loads landed) + BAR (block-wide:
// ALL waves' stages landed — required because waves read rows staged by other
// waves). Then 4 one-barrier phases {reads; stage; BAR; lgkm0; MFMA}.
// Stage order P0->A1(kt+1), P1->B0(kt+1), P2->A0(kt+2), P3->B1(kt+2):
// every same-buffer overwrite issue is >=1 full barrier after its last
// reader's lgkmcnt(0):
//   A0(kt+2)@P2: readers latch in P0 (pre-BAR(P1)); issue post-BAR(P1). OK
//   B1(kt+2)@P3: readers latch in P1 (pre-BAR(P2)); issue post-BAR(P2). OK
//   A1/B0(kt+1): other buffer; last readers one kt earlier; >=2 barriers. OK
// vmcnt queue at kt entry: [A0(kt),B1(kt),A1(kt),B0(kt),A0(kt+1),B1(kt+1)]
// -> vmcnt(4) retires exactly kt's tiles. Prologue tail ordered to match.
#define ABUF_OFF 0
#define BBUF_OFF 65536
#define XAS_OFF  131072
#define LBL_OFF  139264
#define SMEM_BYTES 140288

#define DSREAD(dst, base, imm)                                                 \
  asm volatile("ds_read_b128 %0, %1 offset:%c2"                                \
               : "=v"(dst) : "v"(base), "i"(imm))

#define READ_A(BUFL, a)                                                        \
  {                                                                            \
    DSREAD(af[0][0], baseA0, (BUFL)*32768 + (a)*16384 + 0 * 4096);             \
    DSREAD(af[0][1], baseA1, (BUFL)*32768 + (a)*16384 + 0 * 4096);             \
    DSREAD(af[1][0], baseA0, (BUFL)*32768 + (a)*16384 + 1 * 4096);             \
    DSREAD(af[1][1], baseA1, (BUFL)*32768 + (a)*16384 + 1 * 4096);             \
    DSREAD(af[2][0], baseA0, (BUFL)*32768 + (a)*16384 + 2 * 4096);             \
    DSREAD(af[2][1], baseA1, (BUFL)*32768 + (a)*16384 + 2 * 4096);             \
    DSREAD(af[3][0], baseA0, (BUFL)*32768 + (a)*16384 + 3 * 4096);             \
    DSREAD(af[3][1], baseA1, (BUFL)*32768 + (a)*16384 + 3 * 4096);             \
  }

#define READ_B0(BUFL)                                                          \
  {                                                                            \
    DSREAD(b0f[0][0], baseB0, (BUFL)*32768 + 0 * 16384 + 0 * 8192);            \
    DSREAD(b0f[0][1], baseB1, (BUFL)*32768 + 0 * 16384 + 0 * 8192);            \
    DSREAD(b0f[1][0], baseB0, (BUFL)*32768 + 0 * 16384 + 1 * 8192);            \
    DSREAD(b0f[1][1], baseB1, (BUFL)*32768 + 0 * 16384 + 1 * 8192);            \
  }

#define READ_B1(BUFL)                                                          \
  {                                                                            \
    DSREAD(b1f[0][0], baseB0, (BUFL)*32768 + 1 * 16384 + 0 * 8192);            \
    DSREAD(b1f[0][1], baseB1, (BUFL)*32768 + 1 * 16384 + 0 * 8192);            \
    DSREAD(b1f[1][0], baseB0, (BUFL)*32768 + 1 * 16384 + 1 * 8192);            \
    DSREAD(b1f[1][1], baseB1, (BUFL)*32768 + 1 * 16384 + 1 * 8192);            \
  }

#define MMA(a, BF, b)                                                          \
  {                                                                            \
    __builtin_amdgcn_s_setprio(1);                                             \
    _Pragma("unroll") for (int rm = 0; rm < 4; ++rm)                           \
    _Pragma("unroll") for (int rn = 0; rn < 2; ++rn)                           \
    _Pragma("unroll") for (int kk = 0; kk < 2; ++kk)                           \
      acc[(a) * 4 + rm][(b) * 2 + rn] = __builtin_amdgcn_mfma_f32_16x16x32_bf16( \
          af[rm][kk], BF[rn][kk], acc[(a) * 4 + rm][(b) * 2 + rn], 0, 0, 0);   \
    __builtin_amdgcn_s_setprio(0);                                             \
  }

#define BAR() __builtin_amdgcn_s_barrier()
#define LGKM0() asm volatile("s_waitcnt lgkmcnt(0)" ::: "memory")
#define SBAR0() __builtin_amdgcn_sched_barrier(0)

#define KT_BODY(BUFL, ktv)                                                     \
  {                                                                            \
    const int kn1 = ((ktv) + 1) & 15, kn2 = ((ktv) + 2) & 15;                  \
    asm volatile("s_waitcnt vmcnt(4)" ::: "memory");                           \
    BAR(); /* block-wide: all waves' kt-tiles landed */                        \
    /* P0: reads A0+B0; stage A1(kt+1) */                                      \
    READ_A(BUFL, 0); READ_B0(BUFL);                                            \
    stA(kn1, 1);                                                               \
    SBAR0(); BAR(); LGKM0(); SBAR0();                                          \
    MMA(0, b0f, 0);                                                            \
    /* P1: reads B1; stage B0(kt+1) */                                         \
    READ_B1(BUFL);                                                             \
    stB(kn1, 0);                                                               \
    SBAR0(); BAR(); LGKM0(); SBAR0();                                          \
    MMA(0, b1f, 1);                                                            \
    /* P2: reads A1; stage A0(kt+2) */                                         \
    READ_A(BUFL, 1);                                                           \
    stA(kn2, 0);                                                               \
    SBAR0(); BAR(); LGKM0(); SBAR0();                                          \
    MMA(1, b1f, 1);                                                            \
    /* P3: no reads; stage B1(kt+2) */                                         \
    stB(kn2, 1);                                                               \
    SBAR0(); BAR(); SBAR0();                                                   \
    MMA(1, b0f, 0);                                                            \
  }

__global__ __launch_bounds__(512, 2) void k_gemm(const uint16_t* __restrict__ xb,
                                                 const uint16_t* __restrict__ Wt,
                                                 const uint16_t* __restrict__ Bb,
                                                 const float* __restrict__ xa,
                                                 const int* __restrict__ labels,
                                                 const float* __restrict__ bias,
                                                 float* __restrict__ out) {
  __shared__ __align__(16) uint8_t smem[SMEM_BYTES];
  const int t = threadIdx.x;
  const int wid = t >> 6, lane = t & 63;
  const int wr = wid >> 2, wc = wid & 3;
  const int fr = lane & 15, fq = lane >> 4;
  const int sx = fr & 7;

  // XCD-aware bijective swizzle (nwg = 256, 256 % 8 == 0)
  const int bid = blockIdx.x;
  const int sid = (bid & 7) * 32 + (bid >> 3);
  const int m0 = (sid >> 2) * 256;
  const int n0 = (sid & 3) * 256;

  // stage per-tile token metadata (before pipeline; __syncthreads drains)
  int* lbls = (int*)(smem + LBL_OFF);
  float* xas = (float*)(smem + XAS_OFF);
  if (t < 256) lbls[t] = labels[m0 + t];
  {
    const int r = t >> 1, c = (t & 1) * 4;
    *(float4*)(xas + r * 8 + c) = *(const float4*)(xa + (size_t)(m0 + r) * 8 + c);
  }
  __syncthreads();

  // per-thread LDS read bases (kk=0 / kk=1 slot variants)
  lds_ptr_t baseA0 = (lds_ptr_t)(smem + ABUF_OFF + (wr * 16 + fr) * 128 + ((0 + fq) ^ sx) * 16);
  lds_ptr_t baseA1 = (lds_ptr_t)(smem + ABUF_OFF + (wr * 16 + fr) * 128 + ((4 + fq) ^ sx) * 16);
  lds_ptr_t baseB0 = (lds_ptr_t)(smem + BBUF_OFF + (wc * 16 + fr) * 128 + ((0 + fq) ^ sx) * 16);
  lds_ptr_t baseB1 = (lds_ptr_t)(smem + BBUF_OFF + (wc * 16 + fr) * 128 + ((4 + fq) ^ sx) * 16);

  // staging: per call a wave stages 8 rows (1024B linear LDS); 2 calls = half-tile
  const int srow = wid * 8 + (lane >> 3);                    // row in 64-row chunk
  const int sslot = ((lane & 7) ^ ((lane >> 3) & 7)) * 8;    // inverse-swizzled src
  auto stA = [&](int kt, int h) {
    const int buf = kt & 1;
    const uint16_t* g = xb + (size_t)(m0 + h * 128 + srow) * D_DIM + kt * 64 + sslot;
    uint8_t* l = smem + ABUF_OFF + buf * 32768 + h * 16384 + wid * 1024;
    gld_lds16(g, l);
    gld_lds16(g + (size_t)64 * D_DIM, l + 8192);
  };
  auto stB = [&](int kt, int h) {
    const int buf = kt & 1;
    const uint16_t* g = Wt + (size_t)(n0 + h * 128 + srow) * D_DIM + kt * 64 + sslot;
    uint8_t* l = smem + BBUF_OFF + buf * 32768 + h * 16384 + wid * 1024;
    gld_lds16(g, l);
    gld_lds16(g + (size_t)64 * D_DIM, l + 8192);
  };

  f32x4 acc[8][4] = {};
  bf16x8 af[4][2], b0f[2][2], b1f[2][2];

  // prologue (queue order must be A0(0),B1(0),A1(0),B0(0),A0(1),B1(1))
  stA(0, 0); stB(0, 1); stA(0, 1); stB(0, 0); stA(1, 0); stB(1, 1);
  SBAR0();

  for (int ktp = 0; ktp < 8; ++ktp) {
    KT_BODY(0, ktp * 2);
    KT_BODY(1, ktp * 2 + 1);
  }

  // epilogue: out = acc + bias + SCALE * (xa . Bb[lbl][n][:])
  float bv[4];
#pragma unroll
  for (int rn = 0; rn < 4; ++rn) bv[rn] = bias[n0 + rn * 64 + wc * 16 + fr];

#pragma unroll
  for (int rm = 0; rm < 8; ++rm) {
#pragma unroll
    for (int j = 0; j < 4; ++j) {
      const int ml = rm * 32 + wr * 16 + fq * 4 + j;  // C/D row mapping
      const int grow = m0 + ml;
      const int lbl = lbls[ml];
      const float* xv = xas + ml * 8;
      const float x0 = xv[0], x1 = xv[1], x2 = xv[2], x3 = xv[3];
      const float x4 = xv[4], x5 = xv[5], x6 = xv[6], x7 = xv[7];
#pragma unroll
      for (int rn = 0; rn < 4; ++rn) {
        const int n = n0 + rn * 64 + wc * 16 + fr;    // C/D col mapping
        const bf16x8 bb = *(const bf16x8*)(Bb + ((size_t)lbl * D_DIM + n) * 8);
        float dot = x0 * (float)bb[0] + x1 * (float)bb[1] + x2 * (float)bb[2] +
                    x3 * (float)bb[3] + x4 * (float)bb[4] + x5 * (float)bb[5] +
                    x6 * (float)bb[6] + x7 * (float)bb[7];
        out[(size_t)grow * D_DIM + n] = acc[rm][rn][j] + bv[rn] + SCALE * dot;
      }
    }
  }
}

extern "C" void kernel_launch(void* const* d_in, const int* in_sizes, int n_in,
                              void* d_out, int out_size, void* d_ws, size_t ws_size,
                              hipStream_t stream) {
  (void)in_sizes; (void)n_in; (void)out_size; (void)ws_size;
  const float* x      = (const float*)d_in[0];
  const int*   labels = (const int*)d_in[1];
  const float* W      = (const float*)d_in[2];
  const float* A      = (const float*)d_in[3];
  const float* B      = (const float*)d_in[4];
  const float* bias   = (const float*)d_in[5];
  float* out = (float*)d_out;

  uint8_t* ws = (uint8_t*)d_ws;
  uint16_t* xb = (uint16_t*)ws;                          // 33,554,432 B
  uint16_t* Wt = (uint16_t*)(ws + (size_t)33554432);     //  2,097,152 B
  uint16_t* Bb = (uint16_t*)(ws + (size_t)35651584);     //  1,048,576 B
  float*    xa = (float*)   (ws + (size_t)36700160);     //    524,288 B
  uint16_t* At = (uint16_t*)(ws + (size_t)37224448);     //  1,048,576 B

  k_prep_w<<<dim3(32, 32), 256, 0, stream>>>(W, Wt);
  k_prep_b<<<256, 256, 0, stream>>>(B, Bb);
  k_prep_a<<<256, 256, 0, stream>>>(A, At);
  k_prep_x<<<4096, 256, 0, stream>>>(x, labels, At, xb, xa);
  k_gemm<<<256, 512, 0, stream>>>(xb, Wt, Bb, xa, labels, bias, out);
}